// Round 1
// baseline (278.513 us; speedup 1.0000x reference)
//
#include <hip/hip_runtime.h>
#include <math.h>

#define NN 50000
#define NE 800000

typedef float4 f4;

// K1: P = z@W1^T + b_nbr ; Q = z@W2^T ; C = sigmoid(z@Wc^T + b_cur)
// W_nbr = [W1 | W2] per e = concat(z[dst], z[src]).
__global__ __launch_bounds__(256) void k1_node(
    const float* __restrict__ z,
    const float* __restrict__ Wc, const float* __restrict__ bc,
    const float* __restrict__ Wn, const float* __restrict__ bn,
    float* __restrict__ P, float* __restrict__ Q, float* __restrict__ C)
{
    __shared__ f4 wlds[3 * 16 * 64]; // [(m*16 + k4)*64 + h] = W_m[h][4k4..4k4+3]
    const int tid = threadIdx.x;
    for (int j = tid; j < 3 * 16 * 64; j += 256) {
        const int m = j >> 10, r = j & 1023, h = r >> 4, k4 = r & 15;
        const float* s = (m == 0) ? (Wc + h * 64 + k4 * 4)
                                  : (Wn + h * 128 + (m - 1) * 64 + k4 * 4);
        wlds[(m * 16 + k4) * 64 + h] = *(const f4*)s;
    }
    __syncthreads();

    const int lane = tid & 63;
    const int gw = (blockIdx.x * 256 + tid) >> 6;
    const int nw = (gridDim.x * 256) >> 6;
    const float bcur = bc[lane], bnbr = bn[lane];

    for (int chunk = gw; chunk < NN / 4; chunk += nw) {
        const int n0 = chunk * 4;
        float a0[4] = {0.f, 0.f, 0.f, 0.f};
        float a1[4] = {0.f, 0.f, 0.f, 0.f};
        float a2[4] = {0.f, 0.f, 0.f, 0.f};
        #pragma unroll 4
        for (int k4 = 0; k4 < 16; ++k4) {
            const f4 w0 = wlds[(0 * 16 + k4) * 64 + lane];
            const f4 w1 = wlds[(1 * 16 + k4) * 64 + lane];
            const f4 w2 = wlds[(2 * 16 + k4) * 64 + lane];
            #pragma unroll
            for (int ni = 0; ni < 4; ++ni) {
                const f4 zz = *(const f4*)(z + (n0 + ni) * 64 + k4 * 4);
                a0[ni] = fmaf(w0.w, zz.w, fmaf(w0.z, zz.z, fmaf(w0.y, zz.y, fmaf(w0.x, zz.x, a0[ni]))));
                a1[ni] = fmaf(w1.w, zz.w, fmaf(w1.z, zz.z, fmaf(w1.y, zz.y, fmaf(w1.x, zz.x, a1[ni]))));
                a2[ni] = fmaf(w2.w, zz.w, fmaf(w2.z, zz.z, fmaf(w2.y, zz.y, fmaf(w2.x, zz.x, a2[ni]))));
            }
        }
        #pragma unroll
        for (int ni = 0; ni < 4; ++ni) {
            const int n = n0 + ni;
            C[n * 64 + lane] = 1.0f / (1.0f + __expf(-(a0[ni] + bcur)));
            P[n * 64 + lane] = a1[ni] + bnbr;
            Q[n * 64 + lane] = a2[ni];
        }
    }
}

// K2: per edge, m = sigmoid(P[dst] + Q[src]); atomic scatter-add into NB[dst].
__global__ __launch_bounds__(256) void k2_edge(
    const int* __restrict__ esrc, const int* __restrict__ edst,
    const float* __restrict__ P, const float* __restrict__ Q,
    float* __restrict__ NB)
{
    const int lane = threadIdx.x & 63;
    const int gw = (blockIdx.x * 256 + threadIdx.x) >> 6;
    const int nw = (gridDim.x * 256) >> 6;
    for (int e = gw; e < NE; e += nw) {
        const int d = edst[e], s = esrc[e];
        const float x = P[d * 64 + lane] + Q[s * 64 + lane];
        const float m = 1.0f / (1.0f + __expf(-x));
        atomicAdd(&NB[d * 64 + lane], m);
    }
}

// K3: out = tanh([C | NB] @ W_out^T + b_out)
__global__ __launch_bounds__(256) void k3_out(
    const float* __restrict__ C, const float* __restrict__ NB,
    const float* __restrict__ Wo, const float* __restrict__ bo,
    float* __restrict__ out)
{
    __shared__ f4 wlds[32 * 64]; // [k4*64 + d] = Wo[d][4k4..4k4+3], k in [0,128)
    const int tid = threadIdx.x;
    for (int j = tid; j < 32 * 64; j += 256) {
        const int d = j >> 5, k4 = j & 31;
        wlds[k4 * 64 + d] = *(const f4*)(Wo + d * 128 + k4 * 4);
    }
    __syncthreads();

    const int lane = tid & 63;
    const int gw = (blockIdx.x * 256 + tid) >> 6;
    const int nw = (gridDim.x * 256) >> 6;
    const float bout = bo[lane];

    for (int chunk = gw; chunk < NN / 4; chunk += nw) {
        const int n0 = chunk * 4;
        float acc[4] = {0.f, 0.f, 0.f, 0.f};
        #pragma unroll 4
        for (int k4 = 0; k4 < 32; ++k4) {
            const f4 w = wlds[k4 * 64 + lane];
            const float* base = (k4 < 16) ? C : NB;
            const int koff = (k4 & 15) * 4;
            #pragma unroll
            for (int ni = 0; ni < 4; ++ni) {
                const f4 hv = *(const f4*)(base + (n0 + ni) * 64 + koff);
                acc[ni] = fmaf(w.w, hv.w, fmaf(w.z, hv.z, fmaf(w.y, hv.y, fmaf(w.x, hv.x, acc[ni]))));
            }
        }
        #pragma unroll
        for (int ni = 0; ni < 4; ++ni)
            out[(n0 + ni) * 64 + lane] = tanhf(acc[ni] + bout);
    }
}

extern "C" void kernel_launch(void* const* d_in, const int* in_sizes, int n_in,
                              void* d_out, int out_size, void* d_ws, size_t ws_size,
                              hipStream_t stream) {
    const float* z  = (const float*)d_in[0];
    const int* esrc = (const int*)d_in[1];
    const int* edst = (const int*)d_in[2];
    const float* Wc = (const float*)d_in[3];
    const float* bc = (const float*)d_in[4];
    const float* Wn = (const float*)d_in[5];
    const float* bn = (const float*)d_in[6];
    const float* Wo = (const float*)d_in[7];
    const float* bo = (const float*)d_in[8];
    float* out = (float*)d_out;

    float* P  = (float*)d_ws;          // [NN*64]
    float* Q  = P + (size_t)NN * 64;   // [NN*64]
    float* C  = Q + (size_t)NN * 64;   // [NN*64]
    float* NB = C + (size_t)NN * 64;   // [NN*64]

    hipMemsetAsync(NB, 0, (size_t)NN * 64 * sizeof(float), stream);
    k1_node<<<1024, 256, 0, stream>>>(z, Wc, bc, Wn, bn, P, Q, C);
    k2_edge<<<2048, 256, 0, stream>>>(esrc, edst, P, Q, NB);
    k3_out<<<1024, 256, 0, stream>>>(C, NB, Wo, bo, out);
}

// Round 2
// 254.342 us; speedup vs baseline: 1.0950x; 1.0950x over previous
//
#include <hip/hip_runtime.h>
#include <math.h>

#define NN 50000
#define NE 800000
#define SCAN_B 1024
#define NB_SCAN ((NN + SCAN_B - 1) / SCAN_B)   // 49

typedef float4 f4;

__device__ __forceinline__ float sigf(float x) {
    return 1.0f / (1.0f + __expf(-x));
}

// K1: P = z@W1^T + b_nbr ; Q = z@W2^T ; C = sigmoid(z@Wc^T + b_cur)
__global__ __launch_bounds__(256) void k1_node(
    const float* __restrict__ z,
    const float* __restrict__ Wc, const float* __restrict__ bc,
    const float* __restrict__ Wn, const float* __restrict__ bn,
    float* __restrict__ P, float* __restrict__ Q, float* __restrict__ C)
{
    __shared__ f4 wlds[3 * 16 * 64]; // [(m*16 + k4)*64 + h] = W_m[h][4k4..4k4+3]
    const int tid = threadIdx.x;
    for (int j = tid; j < 3 * 16 * 64; j += 256) {
        const int m = j >> 10, r = j & 1023, h = r >> 4, k4 = r & 15;
        const float* s = (m == 0) ? (Wc + h * 64 + k4 * 4)
                                  : (Wn + h * 128 + (m - 1) * 64 + k4 * 4);
        wlds[(m * 16 + k4) * 64 + h] = *(const f4*)s;
    }
    __syncthreads();

    const int lane = tid & 63;
    const int gw = (blockIdx.x * 256 + tid) >> 6;
    const int nw = (gridDim.x * 256) >> 6;
    const float bcur = bc[lane], bnbr = bn[lane];

    for (int chunk = gw; chunk < NN / 4; chunk += nw) {
        const int n0 = chunk * 4;
        float a0[4] = {0.f, 0.f, 0.f, 0.f};
        float a1[4] = {0.f, 0.f, 0.f, 0.f};
        float a2[4] = {0.f, 0.f, 0.f, 0.f};
        #pragma unroll 4
        for (int k4 = 0; k4 < 16; ++k4) {
            const f4 w0 = wlds[(0 * 16 + k4) * 64 + lane];
            const f4 w1 = wlds[(1 * 16 + k4) * 64 + lane];
            const f4 w2 = wlds[(2 * 16 + k4) * 64 + lane];
            #pragma unroll
            for (int ni = 0; ni < 4; ++ni) {
                const f4 zz = *(const f4*)(z + (n0 + ni) * 64 + k4 * 4);
                a0[ni] = fmaf(w0.w, zz.w, fmaf(w0.z, zz.z, fmaf(w0.y, zz.y, fmaf(w0.x, zz.x, a0[ni]))));
                a1[ni] = fmaf(w1.w, zz.w, fmaf(w1.z, zz.z, fmaf(w1.y, zz.y, fmaf(w1.x, zz.x, a1[ni]))));
                a2[ni] = fmaf(w2.w, zz.w, fmaf(w2.z, zz.z, fmaf(w2.y, zz.y, fmaf(w2.x, zz.x, a2[ni]))));
            }
        }
        #pragma unroll
        for (int ni = 0; ni < 4; ++ni) {
            const int n = n0 + ni;
            C[n * 64 + lane] = sigf(a0[ni] + bcur);
            P[n * 64 + lane] = a1[ni] + bnbr;
            Q[n * 64 + lane] = a2[ni];
        }
    }
}

// Histogram of destination degrees (deg pre-zeroed via memsetAsync).
__global__ __launch_bounds__(256) void k_hist(const int* __restrict__ edst,
                                              int* __restrict__ deg)
{
    for (int e = blockIdx.x * 256 + threadIdx.x; e < NE; e += gridDim.x * 256)
        atomicAdd(&deg[edst[e]], 1);
}

// Scan level 1: per-block (1024 elems) exclusive scan of deg -> off, block sums -> bsum.
__global__ __launch_bounds__(256) void k_scan1(const int* __restrict__ deg,
                                               int* __restrict__ off,
                                               int* __restrict__ bsum)
{
    __shared__ int part[256];
    const int tid = threadIdx.x;
    const int base = blockIdx.x * SCAN_B + tid * 4;
    const int d0 = (base + 0 < NN) ? deg[base + 0] : 0;
    const int d1 = (base + 1 < NN) ? deg[base + 1] : 0;
    const int d2 = (base + 2 < NN) ? deg[base + 2] : 0;
    const int d3 = (base + 3 < NN) ? deg[base + 3] : 0;
    part[tid] = d0 + d1 + d2 + d3;
    __syncthreads();
    for (int o = 1; o < 256; o <<= 1) {
        int v = 0;
        if (tid >= o) v = part[tid - o];
        __syncthreads();
        if (tid >= o) part[tid] += v;
        __syncthreads();
    }
    const int excl = (tid > 0) ? part[tid - 1] : 0;
    if (base + 0 < NN) off[base + 0] = excl;
    if (base + 1 < NN) off[base + 1] = excl + d0;
    if (base + 2 < NN) off[base + 2] = excl + d0 + d1;
    if (base + 3 < NN) off[base + 3] = excl + d0 + d1 + d2;
    if (tid == 255) bsum[blockIdx.x] = part[255];
}

// Scan level 2: exclusive scan of the 49 block sums (single thread; trivial).
__global__ void k_scan2(const int* __restrict__ bsum, int* __restrict__ bpre)
{
    if (threadIdx.x == 0 && blockIdx.x == 0) {
        int r = 0;
        for (int b = 0; b < NB_SCAN; ++b) { bpre[b] = r; r += bsum[b]; }
    }
}

// Scan level 3: add block prefixes; init cursor; off[NN] = NE.
__global__ __launch_bounds__(256) void k_scan3(int* __restrict__ off,
                                               const int* __restrict__ bpre,
                                               int* __restrict__ cursor)
{
    for (int i = blockIdx.x * 256 + threadIdx.x; i < NN; i += gridDim.x * 256) {
        const int v = off[i] + bpre[i >> 10];
        off[i] = v;
        cursor[i] = v;
    }
    if (blockIdx.x == 0 && threadIdx.x == 0) off[NN] = NE;
}

// Scatter edges into dst-sorted order (src indices only).
__global__ __launch_bounds__(256) void k_scatter(const int* __restrict__ esrc,
                                                 const int* __restrict__ edst,
                                                 int* __restrict__ cursor,
                                                 int* __restrict__ ss)
{
    for (int e = blockIdx.x * 256 + threadIdx.x; e < NE; e += gridDim.x * 256) {
        const int d = edst[e];
        const int pos = atomicAdd(&cursor[d], 1);
        ss[pos] = esrc[e];
    }
}

// K2: one wave per dst node; accumulate sigmoid(P[d]+Q[s]) over its segment.
__global__ __launch_bounds__(256) void k2_agg(
    const int* __restrict__ off, const int* __restrict__ ss,
    const float* __restrict__ P, const float* __restrict__ Q,
    float* __restrict__ NB)
{
    const int lane = threadIdx.x & 63;
    const int n = (blockIdx.x * 256 + threadIdx.x) >> 6;
    if (n >= NN) return;
    const int b = off[n], e = off[n + 1];
    const float p = P[n * 64 + lane];
    float acc = 0.f;
    int j = b;
    for (; j + 1 < e; j += 2) {
        const int s0 = ss[j], s1 = ss[j + 1];
        const float q0 = Q[s0 * 64 + lane];
        const float q1 = Q[s1 * 64 + lane];
        acc += sigf(p + q0) + sigf(p + q1);
    }
    if (j < e) acc += sigf(p + Q[ss[j] * 64 + lane]);
    NB[n * 64 + lane] = acc;
}

// K3: out = tanh([C | NB] @ W_out^T + b_out)
__global__ __launch_bounds__(256) void k3_out(
    const float* __restrict__ C, const float* __restrict__ NB,
    const float* __restrict__ Wo, const float* __restrict__ bo,
    float* __restrict__ out)
{
    __shared__ f4 wlds[32 * 64]; // [k4*64 + d] = Wo[d][4k4..4k4+3]
    const int tid = threadIdx.x;
    for (int j = tid; j < 32 * 64; j += 256) {
        const int d = j >> 5, k4 = j & 31;
        wlds[k4 * 64 + d] = *(const f4*)(Wo + d * 128 + k4 * 4);
    }
    __syncthreads();

    const int lane = tid & 63;
    const int gw = (blockIdx.x * 256 + tid) >> 6;
    const int nw = (gridDim.x * 256) >> 6;
    const float bout = bo[lane];

    for (int chunk = gw; chunk < NN / 4; chunk += nw) {
        const int n0 = chunk * 4;
        float acc[4] = {0.f, 0.f, 0.f, 0.f};
        #pragma unroll 4
        for (int k4 = 0; k4 < 32; ++k4) {
            const f4 w = wlds[k4 * 64 + lane];
            const float* base = (k4 < 16) ? C : NB;
            const int koff = (k4 & 15) * 4;
            #pragma unroll
            for (int ni = 0; ni < 4; ++ni) {
                const f4 hv = *(const f4*)(base + (n0 + ni) * 64 + koff);
                acc[ni] = fmaf(w.w, hv.w, fmaf(w.z, hv.z, fmaf(w.y, hv.y, fmaf(w.x, hv.x, acc[ni]))));
            }
        }
        #pragma unroll
        for (int ni = 0; ni < 4; ++ni)
            out[(n0 + ni) * 64 + lane] = tanhf(acc[ni] + bout);
    }
}

extern "C" void kernel_launch(void* const* d_in, const int* in_sizes, int n_in,
                              void* d_out, int out_size, void* d_ws, size_t ws_size,
                              hipStream_t stream) {
    const float* z  = (const float*)d_in[0];
    const int* esrc = (const int*)d_in[1];
    const int* edst = (const int*)d_in[2];
    const float* Wc = (const float*)d_in[3];
    const float* bc = (const float*)d_in[4];
    const float* Wn = (const float*)d_in[5];
    const float* bn = (const float*)d_in[6];
    const float* Wo = (const float*)d_in[7];
    const float* bo = (const float*)d_in[8];
    float* out = (float*)d_out;

    float* P  = (float*)d_ws;          // [NN*64]
    float* Q  = P + (size_t)NN * 64;   // [NN*64]
    float* C  = Q + (size_t)NN * 64;   // [NN*64]
    float* NB = C + (size_t)NN * 64;   // [NN*64]
    int* off    = (int*)(NB + (size_t)NN * 64); // [NN+1] (padded)
    int* cursor = off + (NN + 64);              // [NN]
    int* bsum   = cursor + NN;                  // [64]
    int* bpre   = bsum + 64;                    // [64]
    int* deg    = bpre + 64;                    // [NN]
    int* ss     = deg + NN;                     // [NE]

    hipMemsetAsync(deg, 0, (size_t)NN * sizeof(int), stream);
    k1_node<<<1024, 256, 0, stream>>>(z, Wc, bc, Wn, bn, P, Q, C);
    k_hist<<<400, 256, 0, stream>>>(edst, deg);
    k_scan1<<<NB_SCAN, 256, 0, stream>>>(deg, off, bsum);
    k_scan2<<<1, 64, 0, stream>>>(bsum, bpre);
    k_scan3<<<64, 256, 0, stream>>>(off, bpre, cursor);
    k_scatter<<<400, 256, 0, stream>>>(esrc, edst, cursor, ss);
    k2_agg<<<(NN * 64 + 255) / 256, 256, 0, stream>>>(off, ss, P, Q, NB);
    k3_out<<<1024, 256, 0, stream>>>(C, NB, Wo, bo, out);
}

// Round 3
// 228.077 us; speedup vs baseline: 1.2211x; 1.1152x over previous
//
#include <hip/hip_runtime.h>
#include <math.h>

#define NN 50000
#define NE 800000
#define SCAN_B 1024
#define NB_SCAN ((NN + SCAN_B - 1) / SCAN_B)   // 49
#define EDGE_BLOCKS (NE / 256)                  // 3125, exact

typedef float4 f4;
typedef unsigned short u16;

__device__ __forceinline__ float sigf(float x) {
    return 1.0f / (1.0f + __expf(-x));
}

// K1: P = z@W1^T + b_nbr ; Q = z@W2^T ; C = sigmoid(z@Wc^T + b_cur)
__global__ __launch_bounds__(256) void k1_node(
    const float* __restrict__ z,
    const float* __restrict__ Wc, const float* __restrict__ bc,
    const float* __restrict__ Wn, const float* __restrict__ bn,
    float* __restrict__ P, float* __restrict__ Q, float* __restrict__ C)
{
    __shared__ f4 wlds[3 * 16 * 64]; // [(m*16 + k4)*64 + h] = W_m[h][4k4..4k4+3]
    const int tid = threadIdx.x;
    for (int j = tid; j < 3 * 16 * 64; j += 256) {
        const int m = j >> 10, r = j & 1023, h = r >> 4, k4 = r & 15;
        const float* s = (m == 0) ? (Wc + h * 64 + k4 * 4)
                                  : (Wn + h * 128 + (m - 1) * 64 + k4 * 4);
        wlds[(m * 16 + k4) * 64 + h] = *(const f4*)s;
    }
    __syncthreads();

    const int lane = tid & 63;
    const int gw = (blockIdx.x * 256 + tid) >> 6;
    const int nw = (gridDim.x * 256) >> 6;
    const float bcur = bc[lane], bnbr = bn[lane];

    for (int chunk = gw; chunk < NN / 4; chunk += nw) {
        const int n0 = chunk * 4;
        float a0[4] = {0.f, 0.f, 0.f, 0.f};
        float a1[4] = {0.f, 0.f, 0.f, 0.f};
        float a2[4] = {0.f, 0.f, 0.f, 0.f};
        #pragma unroll 4
        for (int k4 = 0; k4 < 16; ++k4) {
            const f4 w0 = wlds[(0 * 16 + k4) * 64 + lane];
            const f4 w1 = wlds[(1 * 16 + k4) * 64 + lane];
            const f4 w2 = wlds[(2 * 16 + k4) * 64 + lane];
            #pragma unroll
            for (int ni = 0; ni < 4; ++ni) {
                const f4 zz = *(const f4*)(z + (n0 + ni) * 64 + k4 * 4);
                a0[ni] = fmaf(w0.w, zz.w, fmaf(w0.z, zz.z, fmaf(w0.y, zz.y, fmaf(w0.x, zz.x, a0[ni]))));
                a1[ni] = fmaf(w1.w, zz.w, fmaf(w1.z, zz.z, fmaf(w1.y, zz.y, fmaf(w1.x, zz.x, a1[ni]))));
                a2[ni] = fmaf(w2.w, zz.w, fmaf(w2.z, zz.z, fmaf(w2.y, zz.y, fmaf(w2.x, zz.x, a2[ni]))));
            }
        }
        #pragma unroll
        for (int ni = 0; ni < 4; ++ni) {
            const int n = n0 + ni;
            C[n * 64 + lane] = sigf(a0[ni] + bcur);
            P[n * 64 + lane] = a1[ni] + bnbr;
            Q[n * 64 + lane] = a2[ni];
        }
    }
}

// Histogram of destination degrees (deg pre-zeroed). One edge per thread.
__global__ __launch_bounds__(256) void k_hist(const int* __restrict__ edst,
                                              int* __restrict__ deg)
{
    const int e = blockIdx.x * 256 + threadIdx.x;
    atomicAdd(&deg[edst[e]], 1);
}

// Scan level 1: per-block (1024 elems) exclusive scan of deg -> off, block sums -> bsum.
__global__ __launch_bounds__(256) void k_scan1(const int* __restrict__ deg,
                                               int* __restrict__ off,
                                               int* __restrict__ bsum)
{
    __shared__ int part[256];
    const int tid = threadIdx.x;
    const int base = blockIdx.x * SCAN_B + tid * 4;
    const int d0 = (base + 0 < NN) ? deg[base + 0] : 0;
    const int d1 = (base + 1 < NN) ? deg[base + 1] : 0;
    const int d2 = (base + 2 < NN) ? deg[base + 2] : 0;
    const int d3 = (base + 3 < NN) ? deg[base + 3] : 0;
    part[tid] = d0 + d1 + d2 + d3;
    __syncthreads();
    for (int o = 1; o < 256; o <<= 1) {
        int v = 0;
        if (tid >= o) v = part[tid - o];
        __syncthreads();
        if (tid >= o) part[tid] += v;
        __syncthreads();
    }
    const int excl = (tid > 0) ? part[tid - 1] : 0;
    if (base + 0 < NN) off[base + 0] = excl;
    if (base + 1 < NN) off[base + 1] = excl + d0;
    if (base + 2 < NN) off[base + 2] = excl + d0 + d1;
    if (base + 3 < NN) off[base + 3] = excl + d0 + d1 + d2;
    if (tid == 255) bsum[blockIdx.x] = part[255];
}

// Scan level 2: exclusive scan of the 49 block sums.
__global__ void k_scan2(const int* __restrict__ bsum, int* __restrict__ bpre)
{
    if (threadIdx.x == 0 && blockIdx.x == 0) {
        int r = 0;
        for (int b = 0; b < NB_SCAN; ++b) { bpre[b] = r; r += bsum[b]; }
    }
}

// Scan level 3: add block prefixes; init cursor; off[NN] = NE.
__global__ __launch_bounds__(256) void k_scan3(int* __restrict__ off,
                                               const int* __restrict__ bpre,
                                               int* __restrict__ cursor)
{
    for (int i = blockIdx.x * 256 + threadIdx.x; i < NN; i += gridDim.x * 256) {
        const int v = off[i] + bpre[i >> 10];
        off[i] = v;
        cursor[i] = v;
    }
    if (blockIdx.x == 0 && threadIdx.x == 0) off[NN] = NE;
}

// Scatter edges into dst-sorted order (u16 src indices). One edge per thread.
__global__ __launch_bounds__(256) void k_scatter(const int* __restrict__ esrc,
                                                 const int* __restrict__ edst,
                                                 int* __restrict__ cursor,
                                                 u16* __restrict__ ss)
{
    const int e = blockIdx.x * 256 + threadIdx.x;
    const int d = edst[e];
    const int s = esrc[e];
    const int pos = atomicAdd(&cursor[d], 1);
    ss[pos] = (u16)s;
}

// K2: one wave per dst node; accumulate sigmoid(P[d]+Q[s]) over its segment.
__global__ __launch_bounds__(256) void k2_agg(
    const int* __restrict__ off, const u16* __restrict__ ss,
    const float* __restrict__ P, const float* __restrict__ Q,
    float* __restrict__ NB)
{
    const int lane = threadIdx.x & 63;
    const int n = (blockIdx.x * 256 + threadIdx.x) >> 6;
    if (n >= NN) return;
    const int b = off[n], e = off[n + 1];
    const float p = P[n * 64 + lane];
    float acc = 0.f;
    int j = b;
    for (; j + 3 < e; j += 4) {
        const int s0 = ss[j], s1 = ss[j + 1], s2 = ss[j + 2], s3 = ss[j + 3];
        const float q0 = Q[s0 * 64 + lane];
        const float q1 = Q[s1 * 64 + lane];
        const float q2 = Q[s2 * 64 + lane];
        const float q3 = Q[s3 * 64 + lane];
        acc += sigf(p + q0) + sigf(p + q1) + sigf(p + q2) + sigf(p + q3);
    }
    for (; j < e; ++j)
        acc += sigf(p + Q[(int)ss[j] * 64 + lane]);
    NB[n * 64 + lane] = acc;
}

// K3: out = tanh([C | NB] @ W_out^T + b_out)
__global__ __launch_bounds__(256) void k3_out(
    const float* __restrict__ C, const float* __restrict__ NB,
    const float* __restrict__ Wo, const float* __restrict__ bo,
    float* __restrict__ out)
{
    __shared__ f4 wlds[32 * 64]; // [k4*64 + d] = Wo[d][4k4..4k4+3]
    const int tid = threadIdx.x;
    for (int j = tid; j < 32 * 64; j += 256) {
        const int d = j >> 5, k4 = j & 31;
        wlds[k4 * 64 + d] = *(const f4*)(Wo + d * 128 + k4 * 4);
    }
    __syncthreads();

    const int lane = tid & 63;
    const int gw = (blockIdx.x * 256 + tid) >> 6;
    const int nw = (gridDim.x * 256) >> 6;
    const float bout = bo[lane];

    for (int chunk = gw; chunk < NN / 4; chunk += nw) {
        const int n0 = chunk * 4;
        float acc[4] = {0.f, 0.f, 0.f, 0.f};
        #pragma unroll 4
        for (int k4 = 0; k4 < 32; ++k4) {
            const f4 w = wlds[k4 * 64 + lane];
            const float* base = (k4 < 16) ? C : NB;
            const int koff = (k4 & 15) * 4;
            #pragma unroll
            for (int ni = 0; ni < 4; ++ni) {
                const f4 hv = *(const f4*)(base + (n0 + ni) * 64 + koff);
                acc[ni] = fmaf(w.w, hv.w, fmaf(w.z, hv.z, fmaf(w.y, hv.y, fmaf(w.x, hv.x, acc[ni]))));
            }
        }
        #pragma unroll
        for (int ni = 0; ni < 4; ++ni)
            out[(n0 + ni) * 64 + lane] = tanhf(acc[ni] + bout);
    }
}

extern "C" void kernel_launch(void* const* d_in, const int* in_sizes, int n_in,
                              void* d_out, int out_size, void* d_ws, size_t ws_size,
                              hipStream_t stream) {
    const float* z  = (const float*)d_in[0];
    const int* esrc = (const int*)d_in[1];
    const int* edst = (const int*)d_in[2];
    const float* Wc = (const float*)d_in[3];
    const float* bc = (const float*)d_in[4];
    const float* Wn = (const float*)d_in[5];
    const float* bn = (const float*)d_in[6];
    const float* Wo = (const float*)d_in[7];
    const float* bo = (const float*)d_in[8];
    float* out = (float*)d_out;

    float* P  = (float*)d_ws;          // [NN*64]
    float* Q  = P + (size_t)NN * 64;   // [NN*64]
    float* C  = Q + (size_t)NN * 64;   // [NN*64]
    float* NB = C + (size_t)NN * 64;   // [NN*64]
    int* off    = (int*)(NB + (size_t)NN * 64); // [NN+1] (padded)
    int* cursor = off + (NN + 64);              // [NN]
    int* bsum   = cursor + NN;                  // [64]
    int* bpre   = bsum + 64;                    // [64]
    int* deg    = bpre + 64;                    // [NN]
    u16* ss     = (u16*)(deg + NN);             // [NE] u16

    hipMemsetAsync(deg, 0, (size_t)NN * sizeof(int), stream);
    k1_node<<<1024, 256, 0, stream>>>(z, Wc, bc, Wn, bn, P, Q, C);
    k_hist<<<EDGE_BLOCKS, 256, 0, stream>>>(edst, deg);
    k_scan1<<<NB_SCAN, 256, 0, stream>>>(deg, off, bsum);
    k_scan2<<<1, 64, 0, stream>>>(bsum, bpre);
    k_scan3<<<64, 256, 0, stream>>>(off, bpre, cursor);
    k_scatter<<<EDGE_BLOCKS, 256, 0, stream>>>(esrc, edst, cursor, ss);
    k2_agg<<<(NN * 64 + 255) / 256, 256, 0, stream>>>(off, ss, P, Q, NB);
    k3_out<<<1024, 256, 0, stream>>>(C, NB, Wo, bo, out);
}